// Round 1
// baseline (4036.422 us; speedup 1.0000x reference)
//
#include <hip/hip_runtime.h>

// Problem: DepthFlowProjectionModule — B=4, H=1080, W=1920, fp32.
// out (B,2,H,W) accumulated via atomics; cnt (B,H,W) in workspace.

#define TPB 256

__global__ void splat_kernel(const float* __restrict__ flow,
                             const float* __restrict__ depth,
                             float* __restrict__ out,
                             float* __restrict__ cnt,
                             int B, int H, int W) {
    int i = blockIdx.x * blockDim.x + threadIdx.x;
    int HWp = H * W;
    int total = B * HWp;
    if (i >= total) return;
    int b = i / HWp;
    int p = i - b * HWp;
    int y = p / W;
    int x = p - y * W;
    const float* fb = flow + (size_t)b * 2 * HWp;
    float fx = fb[p];
    float fy = fb[HWp + p];
    float x2 = (float)x + fx;
    float y2 = (float)y + fy;
    // reference: valid = (x2>=0)&(y2>=0)&(x2<=W-1)&(y2<=H-1); w=0 otherwise -> adds of 0 -> skip
    if (!(x2 >= 0.0f && y2 >= 0.0f && x2 <= (float)(W - 1) && y2 <= (float)(H - 1)))
        return;
    float w = depth[i];
    // trunc-toward-zero == floor here since x2,y2 >= 0 (matches jnp astype(int32) + clip)
    int ixL = (int)x2; if (ixL > W - 1) ixL = W - 1;
    int iyT = (int)y2; if (iyT > H - 1) iyT = H - 1;
    int ixR = min(ixL + 1, W - 1);
    int iyB = min(iyT + 1, H - 1);
    float ax = -fx * w;
    float ay = -fy * w;
    float* cb = cnt + (size_t)b * HWp;
    float* ox = out + (size_t)b * 2 * HWp;
    float* oy = ox + HWp;
    int i00 = iyT * W + ixL;
    int i01 = iyT * W + ixR;
    int i10 = iyB * W + ixL;
    int i11 = iyB * W + ixR;
    // reference tiles the SAME weight to all 4 corners (duplicates double-add at edges;
    // atomicAdd twice reproduces that exactly)
    atomicAdd(&cb[i00], w);
    atomicAdd(&cb[i01], w);
    atomicAdd(&cb[i10], w);
    atomicAdd(&cb[i11], w);
    atomicAdd(&ox[i00], ax);
    atomicAdd(&ox[i01], ax);
    atomicAdd(&ox[i10], ax);
    atomicAdd(&ox[i11], ax);
    atomicAdd(&oy[i00], ay);
    atomicAdd(&oy[i01], ay);
    atomicAdd(&oy[i10], ay);
    atomicAdd(&oy[i11], ay);
}

__global__ void norm_kernel(float* __restrict__ out,
                            const float* __restrict__ cnt,
                            int B, int H, int W) {
    int i = blockIdx.x * blockDim.x + threadIdx.x;
    int HWp = H * W;
    int total = B * HWp;
    if (i >= total) return;
    float c = cnt[i];
    if (c > 0.0f) {
        int b = i / HWp;
        int p = i - b * HWp;
        float* ox = out + (size_t)b * 2 * HWp;
        ox[p] = ox[p] / c;
        ox[HWp + p] = ox[HWp + p] / c;
    }
}

__global__ void fill_kernel(float* __restrict__ out,
                            const float* __restrict__ cnt,
                            int B, int H, int W) {
    int i = blockIdx.x * blockDim.x + threadIdx.x;
    int HWp = H * W;
    int total = B * HWp;
    if (i >= total) return;
    if (cnt[i] > 0.0f) return;          // not a hole
    int b = i / HWp;
    int p = i - b * HWp;
    int y = p / W;
    int x = p - y * W;
    const float* cb = cnt + (size_t)b * HWp;
    float* ox = out + (size_t)b * 2 * HWp;
    float* oy = ox + HWp;
    float nx = 0.0f, ny = 0.0f;
    int den = 0;
    // nearest covered pixel in each of 4 directions (holes are sparse with this input)
    for (int xx = x - 1; xx >= 0; --xx) {
        int q = y * W + xx;
        if (cb[q] > 0.0f) { nx += ox[q]; ny += oy[q]; ++den; break; }
    }
    for (int xx = x + 1; xx < W; ++xx) {
        int q = y * W + xx;
        if (cb[q] > 0.0f) { nx += ox[q]; ny += oy[q]; ++den; break; }
    }
    for (int yy = y - 1; yy >= 0; --yy) {
        int q = yy * W + x;
        if (cb[q] > 0.0f) { nx += ox[q]; ny += oy[q]; ++den; break; }
    }
    for (int yy = y + 1; yy < H; ++yy) {
        int q = yy * W + x;
        if (cb[q] > 0.0f) { nx += ox[q]; ny += oy[q]; ++den; break; }
    }
    if (den > 0) {
        float fd = (float)den;
        ox[p] = nx / fd;
        oy[p] = ny / fd;
    }
    // den==0: keep out (zero), matching reference's where(hole & den>0, ...)
}

extern "C" void kernel_launch(void* const* d_in, const int* in_sizes, int n_in,
                              void* d_out, int out_size, void* d_ws, size_t ws_size,
                              hipStream_t stream) {
    const float* flow  = (const float*)d_in[0];   // (B,2,H,W)
    const float* depth = (const float*)d_in[1];   // (B,1,H,W)
    float* out = (float*)d_out;                   // (B,2,H,W)
    float* cnt = (float*)d_ws;                    // (B,H,W)

    const int H = 1080, W = 1920;
    const int HWp = H * W;
    const int B = in_sizes[1] / HWp;
    const int total = B * HWp;

    // zero accumulators (harness poisons d_out/d_ws with 0xAA)
    hipMemsetAsync(d_out, 0, (size_t)out_size * sizeof(float), stream);
    hipMemsetAsync(d_ws, 0, (size_t)total * sizeof(float), stream);

    int blocks = (total + TPB - 1) / TPB;
    splat_kernel<<<blocks, TPB, 0, stream>>>(flow, depth, out, cnt, B, H, W);
    norm_kernel<<<blocks, TPB, 0, stream>>>(out, cnt, B, H, W);
    fill_kernel<<<blocks, TPB, 0, stream>>>(out, cnt, B, H, W);
}

// Round 3
// 968.191 us; speedup vs baseline: 4.1690x; 4.1690x over previous
//
#include <hip/hip_runtime.h>

// DepthFlowProjectionModule — B=4, H=1080, W=1920, fp32.
// Round 3 = Round 2 resubmit (container was unresponsive; no result obtained).
// LDS-privatized splat. In-tile splats -> LDS atomics; escapes ->
// overflow planes (global atomic); flush = plain coalesced store (tiles
// partition the image, overflow is separate -> no race). merge_norm combines.

#define TW 80
#define TH 64
#define PS (TW * TH + 1)   // plane stride (+1 float: de-bank-align the 3 planes)
#define BLK 1024

__global__ __launch_bounds__(BLK, 2) void splat_tile(
    const float* __restrict__ flow, const float* __restrict__ depth,
    float* __restrict__ out, float* __restrict__ cnt_main,
    float* __restrict__ cnt_ovf, float* __restrict__ ox_ovf,
    float* __restrict__ oy_ovf,
    int B, int H, int W, int use_ovf)
{
    __shared__ float lds[3 * PS];   // 3*(5121)*4 = 61452 B
    float* lc = lds;
    float* lax = lds + PS;
    float* lay = lds + 2 * PS;

    int tid = threadIdx.x;
    for (int q = tid; q < 3 * PS; q += BLK) lds[q] = 0.0f;
    __syncthreads();

    int x0 = blockIdx.x * TW;
    int y0 = blockIdx.y * TH;
    int b  = blockIdx.z;
    int HWp = H * W;
    const float* fb = flow + (size_t)b * 2 * HWp;
    const float* db = depth + (size_t)b * HWp;
    float* co = cnt_ovf + (size_t)b * HWp;
    float* xo = ox_ovf + (size_t)b * HWp;
    float* yo = oy_ovf + (size_t)b * HWp;
    float* cm = cnt_main + (size_t)b * HWp;
    float* oxm = out + (size_t)b * 2 * HWp;
    float* oym = oxm + HWp;

    for (int q = tid; q < TW * TH; q += BLK) {
        int lyy = q / TW, lxx = q - lyy * TW;
        int gx = x0 + lxx, gy = y0 + lyy;
        if (gx >= W || gy >= H) continue;
        int p = gy * W + gx;
        float fx = fb[p], fy = fb[HWp + p];
        float x2 = (float)gx + fx;
        float y2 = (float)gy + fy;
        if (!(x2 >= 0.0f && y2 >= 0.0f && x2 <= (float)(W - 1) && y2 <= (float)(H - 1)))
            continue;
        float w = db[p];
        int ixL = min((int)x2, W - 1);   // x2>=0 -> trunc == floor == jnp astype+clip
        int iyT = min((int)y2, H - 1);
        int ixR = min(ixL + 1, W - 1);
        int iyB = min(iyT + 1, H - 1);
        float ax = -fx * w, ay = -fy * w;
        #pragma unroll
        for (int c = 0; c < 4; ++c) {
            int ix = (c & 1) ? ixR : ixL;
            int iy = (c & 2) ? iyB : iyT;
            int tx = ix - x0, ty = iy - y0;
            if (tx >= 0 && tx < TW && ty >= 0 && ty < TH) {
                int l = ty * TW + tx;
                atomicAdd(&lc[l], w);
                atomicAdd(&lax[l], ax);
                atomicAdd(&lay[l], ay);
            } else {
                int g = iy * W + ix;
                if (use_ovf) {
                    atomicAdd(&co[g], w);
                    atomicAdd(&xo[g], ax);
                    atomicAdd(&yo[g], ay);
                } else {
                    atomicAdd(&cm[g], w);
                    atomicAdd(&oxm[g], ax);
                    atomicAdd(&oym[g], ay);
                }
            }
        }
    }
    __syncthreads();

    // flush LDS tile. use_ovf: plain store (exclusive ownership, main arrays
    // never touched by other blocks). else: atomicAdd into pre-zeroed arrays.
    for (int q = tid; q < TW * TH; q += BLK) {
        int lyy = q / TW, lxx = q - lyy * TW;
        int gx = x0 + lxx, gy = y0 + lyy;
        if (gx >= W || gy >= H) continue;
        int g = gy * W + gx;
        if (use_ovf) {
            cm[g]  = lc[q];
            oxm[g] = lax[q];
            oym[g] = lay[q];
        } else {
            float v = lc[q];
            if (v != 0.0f) {
                atomicAdd(&cm[g], v);
                atomicAdd(&oxm[g], lax[q]);
                atomicAdd(&oym[g], lay[q]);
            }
        }
    }
}

__global__ void merge_norm(float* __restrict__ out, float* __restrict__ cnt_main,
                           const float* __restrict__ cnt_ovf,
                           const float* __restrict__ ox_ovf,
                           const float* __restrict__ oy_ovf,
                           int B, int HWp, int use_ovf)
{
    int i = blockIdx.x * blockDim.x + threadIdx.x;
    int total = B * HWp;
    if (i >= total) return;
    int b = i / HWp;
    int p = i - b * HWp;
    float* oxp = out + (size_t)b * 2 * HWp;
    float c = cnt_main[i];
    float ox = oxp[p], oy = oxp[HWp + p];
    if (use_ovf) {
        c  += cnt_ovf[i];
        ox += ox_ovf[i];
        oy += oy_ovf[i];
    }
    if (c > 0.0f) { ox /= c; oy /= c; }
    oxp[p] = ox;
    oxp[HWp + p] = oy;
    if (use_ovf) cnt_main[i] = c;
}

__global__ void fill_kernel(float* __restrict__ out,
                            const float* __restrict__ cnt,
                            int B, int H, int W)
{
    int i = blockIdx.x * blockDim.x + threadIdx.x;
    int HWp = H * W;
    int total = B * HWp;
    if (i >= total) return;
    if (cnt[i] > 0.0f) return;  // not a hole
    int b = i / HWp;
    int p = i - b * HWp;
    int y = p / W;
    int x = p - y * W;
    const float* cb = cnt + (size_t)b * HWp;
    float* ox = out + (size_t)b * 2 * HWp;
    float* oy = ox + HWp;
    float nx = 0.0f, ny = 0.0f;
    int den = 0;
    for (int xx = x - 1; xx >= 0; --xx) {
        int q = y * W + xx;
        if (cb[q] > 0.0f) { nx += ox[q]; ny += oy[q]; ++den; break; }
    }
    for (int xx = x + 1; xx < W; ++xx) {
        int q = y * W + xx;
        if (cb[q] > 0.0f) { nx += ox[q]; ny += oy[q]; ++den; break; }
    }
    for (int yy = y - 1; yy >= 0; --yy) {
        int q = yy * W + x;
        if (cb[q] > 0.0f) { nx += ox[q]; ny += oy[q]; ++den; break; }
    }
    for (int yy = y + 1; yy < H; ++yy) {
        int q = yy * W + x;
        if (cb[q] > 0.0f) { nx += ox[q]; ny += oy[q]; ++den; break; }
    }
    if (den > 0) {
        float fd = (float)den;
        ox[p] = nx / fd;
        oy[p] = ny / fd;
    }
}

extern "C" void kernel_launch(void* const* d_in, const int* in_sizes, int n_in,
                              void* d_out, int out_size, void* d_ws, size_t ws_size,
                              hipStream_t stream) {
    const float* flow  = (const float*)d_in[0];   // (B,2,H,W)
    const float* depth = (const float*)d_in[1];   // (B,1,H,W)
    float* out = (float*)d_out;                   // (B,2,H,W)

    const int H = 1080, W = 1920;
    const int HWp = H * W;
    const int B = in_sizes[1] / HWp;
    const int total = B * HWp;

    // ws layout: [cnt_main][cnt_ovf][ox_ovf][oy_ovf], each B*H*W floats
    float* cnt_main = (float*)d_ws;
    size_t plane = (size_t)total;
    int use_ovf = (ws_size >= 4 * plane * sizeof(float)) ? 1 : 0;
    float* cnt_ovf = cnt_main + plane;
    float* ox_ovf  = cnt_main + 2 * plane;
    float* oy_ovf  = cnt_main + 3 * plane;

    if (use_ovf) {
        // only overflow planes need zeroing; main arrays are fully stored by flush
        hipMemsetAsync(cnt_ovf, 0, 3 * plane * sizeof(float), stream);
    } else {
        cnt_ovf = cnt_main; ox_ovf = cnt_main; oy_ovf = cnt_main;  // unused
        hipMemsetAsync(d_out, 0, (size_t)out_size * sizeof(float), stream);
        hipMemsetAsync(cnt_main, 0, plane * sizeof(float), stream);
    }

    dim3 grid((W + TW - 1) / TW, (H + TH - 1) / TH, B);
    splat_tile<<<grid, BLK, 0, stream>>>(flow, depth, out, cnt_main,
                                         cnt_ovf, ox_ovf, oy_ovf,
                                         B, H, W, use_ovf);

    int blocks = (total + 255) / 256;
    merge_norm<<<blocks, 256, 0, stream>>>(out, cnt_main, cnt_ovf, ox_ovf, oy_ovf,
                                           B, HWp, use_ovf);
    fill_kernel<<<blocks, 256, 0, stream>>>(out, cnt_main, B, H, W);
}

// Round 4
// 695.340 us; speedup vs baseline: 5.8050x; 1.3924x over previous
//
#include <hip/hip_runtime.h>

// DepthFlowProjectionModule — B=4, H=1080, W=1920, fp32.
// Round 4: 3-pass plane-split LDS privatization. Each pass privatizes ONE
// accumulator plane (cnt / ox / oy) in a 128x120 LDS tile (61.4 KB, 2 blocks/CU),
// cutting escape (scattered-global-atomic) fraction 17.8% -> 10.3% and total
// scattered atomics 51M -> ~10M (the measured cost driver, ~15 ns each).
// Escapes -> overflow planes (atomic); flush -> plain coalesced store
// (tiles partition the image). merge_norm combines, fill_kernel fills holes.

#define TW 128
#define TH 120
#define TPIX (TW * TH)    // 15360 floats = 61440 B LDS
#define BLK 1024

__global__ __launch_bounds__(BLK, 2) void splat_pass(
    const float* __restrict__ flow, const float* __restrict__ depth,
    float* __restrict__ cnt_main, float* __restrict__ out,
    float* __restrict__ ovf,      // 3 planes of B*HW: [cnt][ox][oy]
    int B, int H, int W)
{
    __shared__ float lds[TPIX];
    int tid = threadIdx.x;
    #pragma unroll
    for (int k = 0; k < TPIX / BLK; ++k) lds[tid + k * BLK] = 0.0f;
    __syncthreads();

    int x0 = blockIdx.x * TW;
    int y0 = blockIdx.y * TH;
    int z = blockIdx.z;
    int pass = z / B;             // 0:cnt 1:ox 2:oy
    int b = z - pass * B;
    int HWp = H * W;
    const float* fb = flow + (size_t)b * 2 * HWp;
    const float* db = depth + (size_t)b * HWp;
    float* mp = (pass == 0) ? (cnt_main + (size_t)b * HWp)
              : (pass == 1) ? (out + (size_t)b * 2 * HWp)
                            : (out + (size_t)b * 2 * HWp + HWp);
    float* op = ovf + ((size_t)pass * B + b) * HWp;

    // exact tiling: 1920 = 15*128, 1080 = 9*120 -> no bounds checks
    #pragma unroll
    for (int k = 0; k < TPIX / BLK; ++k) {
        int q = tid + k * BLK;
        int lyy = q >> 7;          // TW = 128
        int lxx = q & (TW - 1);
        int gx = x0 + lxx, gy = y0 + lyy;
        int p = gy * W + gx;
        float fx = fb[p], fy = fb[HWp + p];
        float x2 = (float)gx + fx;
        float y2 = (float)gy + fy;
        if (!(x2 >= 0.0f && y2 >= 0.0f && x2 <= (float)(W - 1) && y2 <= (float)(H - 1)))
            continue;
        float w = db[p];
        float v = (pass == 0) ? w : (pass == 1) ? (-fx * w) : (-fy * w);
        int ixL = min((int)x2, W - 1);   // x2>=0 -> trunc == floor == jnp astype+clip
        int iyT = min((int)y2, H - 1);
        int ixR = min(ixL + 1, W - 1);
        int iyB = min(iyT + 1, H - 1);
        #pragma unroll
        for (int c = 0; c < 4; ++c) {
            int ix = (c & 1) ? ixR : ixL;
            int iy = (c & 2) ? iyB : iyT;
            int tx = ix - x0, ty = iy - y0;
            if ((unsigned)tx < (unsigned)TW && (unsigned)ty < (unsigned)TH) {
                atomicAdd(&lds[(ty << 7) + tx], v);
            } else {
                atomicAdd(&op[iy * W + ix], v);
            }
        }
    }
    __syncthreads();

    // flush: plain coalesced store — this block exclusively owns its tile of mp
    #pragma unroll
    for (int k = 0; k < TPIX / BLK; ++k) {
        int q = tid + k * BLK;
        int lyy = q >> 7;
        int lxx = q & (TW - 1);
        mp[(y0 + lyy) * W + x0 + lxx] = lds[q];
    }
}

// fallback (ws too small): direct global atomics, known-correct from round 1
__global__ void splat_naive(const float* __restrict__ flow,
                            const float* __restrict__ depth,
                            float* __restrict__ out, float* __restrict__ cnt,
                            int B, int H, int W)
{
    int i = blockIdx.x * blockDim.x + threadIdx.x;
    int HWp = H * W;
    if (i >= B * HWp) return;
    int b = i / HWp;
    int p = i - b * HWp;
    int y = p / W;
    int x = p - y * W;
    const float* fb = flow + (size_t)b * 2 * HWp;
    float fx = fb[p], fy = fb[HWp + p];
    float x2 = (float)x + fx, y2 = (float)y + fy;
    if (!(x2 >= 0.0f && y2 >= 0.0f && x2 <= (float)(W - 1) && y2 <= (float)(H - 1)))
        return;
    float w = depth[i];
    int ixL = min((int)x2, W - 1);
    int iyT = min((int)y2, H - 1);
    int ixR = min(ixL + 1, W - 1);
    int iyB = min(iyT + 1, H - 1);
    float ax = -fx * w, ay = -fy * w;
    float* cb = cnt + (size_t)b * HWp;
    float* ox = out + (size_t)b * 2 * HWp;
    float* oy = ox + HWp;
    int idx[4] = {iyT * W + ixL, iyT * W + ixR, iyB * W + ixL, iyB * W + ixR};
    #pragma unroll
    for (int c = 0; c < 4; ++c) {
        atomicAdd(&cb[idx[c]], w);
        atomicAdd(&ox[idx[c]], ax);
        atomicAdd(&oy[idx[c]], ay);
    }
}

__global__ void merge_norm(float* __restrict__ out, float* __restrict__ cnt_main,
                           const float* __restrict__ cnt_ovf,
                           const float* __restrict__ ox_ovf,
                           const float* __restrict__ oy_ovf,
                           int B, int HWp, int use_ovf)
{
    int i = blockIdx.x * blockDim.x + threadIdx.x;
    if (i >= B * HWp) return;
    int b = i / HWp;
    int p = i - b * HWp;
    float* oxp = out + (size_t)b * 2 * HWp;
    float c = cnt_main[i];
    float ox = oxp[p], oy = oxp[HWp + p];
    if (use_ovf) {
        c  += cnt_ovf[i];
        ox += ox_ovf[i];
        oy += oy_ovf[i];
    }
    if (c > 0.0f) { ox /= c; oy /= c; }
    oxp[p] = ox;
    oxp[HWp + p] = oy;
    if (use_ovf) cnt_main[i] = c;
}

__global__ void fill_kernel(float* __restrict__ out,
                            const float* __restrict__ cnt,
                            int B, int H, int W)
{
    int i = blockIdx.x * blockDim.x + threadIdx.x;
    int HWp = H * W;
    if (i >= B * HWp) return;
    if (cnt[i] > 0.0f) return;  // not a hole
    int b = i / HWp;
    int p = i - b * HWp;
    int y = p / W;
    int x = p - y * W;
    const float* cb = cnt + (size_t)b * HWp;
    float* ox = out + (size_t)b * 2 * HWp;
    float* oy = ox + HWp;
    float nx = 0.0f, ny = 0.0f;
    int den = 0;
    for (int xx = x - 1; xx >= 0; --xx) {
        int q = y * W + xx;
        if (cb[q] > 0.0f) { nx += ox[q]; ny += oy[q]; ++den; break; }
    }
    for (int xx = x + 1; xx < W; ++xx) {
        int q = y * W + xx;
        if (cb[q] > 0.0f) { nx += ox[q]; ny += oy[q]; ++den; break; }
    }
    for (int yy = y - 1; yy >= 0; --yy) {
        int q = yy * W + x;
        if (cb[q] > 0.0f) { nx += ox[q]; ny += oy[q]; ++den; break; }
    }
    for (int yy = y + 1; yy < H; ++yy) {
        int q = yy * W + x;
        if (cb[q] > 0.0f) { nx += ox[q]; ny += oy[q]; ++den; break; }
    }
    if (den > 0) {
        float fd = (float)den;
        ox[p] = nx / fd;
        oy[p] = ny / fd;
    }
}

extern "C" void kernel_launch(void* const* d_in, const int* in_sizes, int n_in,
                              void* d_out, int out_size, void* d_ws, size_t ws_size,
                              hipStream_t stream) {
    const float* flow  = (const float*)d_in[0];   // (B,2,H,W)
    const float* depth = (const float*)d_in[1];   // (B,1,H,W)
    float* out = (float*)d_out;                   // (B,2,H,W)

    const int H = 1080, W = 1920;
    const int HWp = H * W;
    const int B = in_sizes[1] / HWp;
    const int total = B * HWp;

    // ws layout: [cnt_main][ovf_cnt][ovf_x][ovf_y], each B*H*W floats
    float* cnt_main = (float*)d_ws;
    size_t plane = (size_t)total;
    float* ovf = cnt_main + plane;
    int blocks = (total + 255) / 256;
    bool tiled = (ws_size >= 4 * plane * sizeof(float)) &&
                 (W % TW == 0) && (H % TH == 0);

    if (tiled) {
        // only overflow planes need zeroing; main planes fully stored by flush
        hipMemsetAsync(ovf, 0, 3 * plane * sizeof(float), stream);
        dim3 grid(W / TW, H / TH, 3 * B);   // 15 x 9 x 12
        splat_pass<<<grid, BLK, 0, stream>>>(flow, depth, cnt_main, out, ovf,
                                             B, H, W);
        merge_norm<<<blocks, 256, 0, stream>>>(out, cnt_main,
                                               ovf, ovf + plane, ovf + 2 * plane,
                                               B, HWp, 1);
    } else {
        hipMemsetAsync(out, 0, (size_t)out_size * sizeof(float), stream);
        hipMemsetAsync(cnt_main, 0, plane * sizeof(float), stream);
        splat_naive<<<blocks, 256, 0, stream>>>(flow, depth, out, cnt_main, B, H, W);
        merge_norm<<<blocks, 256, 0, stream>>>(out, cnt_main,
                                               cnt_main, cnt_main, cnt_main,
                                               B, HWp, 0);
    }
    fill_kernel<<<blocks, 256, 0, stream>>>(out, cnt_main, B, H, W);
}

// Round 5
// 663.133 us; speedup vs baseline: 6.0869x; 1.0486x over previous
//
#include <hip/hip_runtime.h>

// DepthFlowProjectionModule — B=4, H=1080, W=1920, fp32.
// Round 5: owner-gather splat. Each block owns an 80x60 tile with ALL 3
// accumulator planes in LDS (57.6KB, 2 blocks/CU) and reads the expanded
// 128x112 input region (halo 24 in x, 26 in y). A corner is accumulated in
// LDS by the block whose tile contains it IFF |corner-pixel|inf <= halo
// (then the pixel is provably inside that block's expanded region ->
// counted exactly once; flush = plain exclusive store). Rare far corners
// (Gaussian tail beyond halo, ~170K of 33M) go to overflow planes via the
// pixel's HOME block using the identical integer predicate -> no double
// count, no miss. This removes the 10.3M scattered atomics (~385us at the
// measured 26.7 G atomics/s ceiling) from Round 4.

#define TW 80
#define TH 60
#define HX 24
#define HY 26
#define EW 128            // TW + 2*HX (power of 2: ex = q&127, ey = q>>7)
#define EH 112            // TH + 2*HY ; EW*EH = 14336 = 14*1024 exact
#define TPIX (TW * TH)    // 4800 per plane; 3 planes = 57600 B LDS
#define BLK 1024

__global__ __launch_bounds__(BLK, 2) void splat_gather(
    const float* __restrict__ flow, const float* __restrict__ depth,
    float* __restrict__ cnt_main, float* __restrict__ out,
    float* __restrict__ ovf,      // 3 planes of B*HW: [cnt][ox][oy]
    int B, int H, int W)
{
    __shared__ float lds[3 * TPIX];
    float* lc = lds;
    float* lx = lds + TPIX;
    float* ly = lds + 2 * TPIX;

    int tid = threadIdx.x;
    for (int q = tid; q < 3 * TPIX; q += BLK) lds[q] = 0.0f;
    __syncthreads();

    int x0 = blockIdx.x * TW;
    int y0 = blockIdx.y * TH;
    int b  = blockIdx.z;
    int HWp = H * W;
    const float* fb = flow + (size_t)b * 2 * HWp;
    const float* db = depth + (size_t)b * HWp;
    float* cm  = cnt_main + (size_t)b * HWp;
    float* oxm = out + (size_t)b * 2 * HWp;
    float* oym = oxm + HWp;
    float* oc = ovf + (size_t)b * HWp;
    float* oxo = ovf + ((size_t)B + b) * HWp;
    float* oyo = ovf + ((size_t)2 * B + b) * HWp;

    #pragma unroll
    for (int k = 0; k < (EW * EH) / BLK; ++k) {   // 14 exact iterations
        int q = tid + k * BLK;
        int ex = q & (EW - 1);
        int ey = q >> 7;
        int gx = x0 - HX + ex;
        int gy = y0 - HY + ey;
        if ((unsigned)gx >= (unsigned)W || (unsigned)gy >= (unsigned)H) continue;
        int p = gy * W + gx;
        float fx = fb[p], fy = fb[HWp + p];
        float x2 = (float)gx + fx;
        float y2 = (float)gy + fy;
        if (!(x2 >= 0.0f && y2 >= 0.0f && x2 <= (float)(W - 1) && y2 <= (float)(H - 1)))
            continue;
        float w = db[p];
        int ixL = min((int)x2, W - 1);   // x2>=0 -> trunc == floor == jnp astype+clip
        int iyT = min((int)y2, H - 1);
        int ixR = min(ixL + 1, W - 1);
        int iyB = min(iyT + 1, H - 1);
        float vc = w, vx = -fx * w, vy = -fy * w;
        bool in_core = ((unsigned)(gx - x0) < (unsigned)TW) &&
                       ((unsigned)(gy - y0) < (unsigned)TH);
        #pragma unroll
        for (int c = 0; c < 4; ++c) {
            int ix = (c & 1) ? ixR : ixL;
            int iy = (c & 2) ? iyB : iyT;
            // integer predicate, identical in owner and home blocks
            bool near = (abs(ix - gx) <= HX) && (abs(iy - gy) <= HY);
            int tx = ix - x0, ty = iy - y0;
            bool mine = ((unsigned)tx < (unsigned)TW) && ((unsigned)ty < (unsigned)TH);
            if (near && mine) {
                int l = ty * TW + tx;
                atomicAdd(&lc[l], vc);
                atomicAdd(&lx[l], vx);
                atomicAdd(&ly[l], vy);
            } else if (!near && in_core) {
                int g = iy * W + ix;
                atomicAdd(&oc[g], vc);
                atomicAdd(&oxo[g], vx);
                atomicAdd(&oyo[g], vy);
            }
        }
    }
    __syncthreads();

    // flush: plain coalesced store — this block exclusively owns its tile
    for (int q = tid; q < TPIX; q += BLK) {
        int oy_ = q / TW;
        int ox_ = q - oy_ * TW;
        int g = (y0 + oy_) * W + x0 + ox_;
        cm[g]  = lc[q];
        oxm[g] = lx[q];
        oym[g] = ly[q];
    }
}

// fallback (ws too small / shape mismatch): direct global atomics
__global__ void splat_naive(const float* __restrict__ flow,
                            const float* __restrict__ depth,
                            float* __restrict__ out, float* __restrict__ cnt,
                            int B, int H, int W)
{
    int i = blockIdx.x * blockDim.x + threadIdx.x;
    int HWp = H * W;
    if (i >= B * HWp) return;
    int b = i / HWp;
    int p = i - b * HWp;
    int y = p / W;
    int x = p - y * W;
    const float* fb = flow + (size_t)b * 2 * HWp;
    float fx = fb[p], fy = fb[HWp + p];
    float x2 = (float)x + fx, y2 = (float)y + fy;
    if (!(x2 >= 0.0f && y2 >= 0.0f && x2 <= (float)(W - 1) && y2 <= (float)(H - 1)))
        return;
    float w = depth[i];
    int ixL = min((int)x2, W - 1);
    int iyT = min((int)y2, H - 1);
    int ixR = min(ixL + 1, W - 1);
    int iyB = min(iyT + 1, H - 1);
    float ax = -fx * w, ay = -fy * w;
    float* cb = cnt + (size_t)b * HWp;
    float* ox = out + (size_t)b * 2 * HWp;
    float* oy = ox + HWp;
    int idx[4] = {iyT * W + ixL, iyT * W + ixR, iyB * W + ixL, iyB * W + ixR};
    #pragma unroll
    for (int c = 0; c < 4; ++c) {
        atomicAdd(&cb[idx[c]], w);
        atomicAdd(&ox[idx[c]], ax);
        atomicAdd(&oy[idx[c]], ay);
    }
}

__global__ void merge_norm(float* __restrict__ out, float* __restrict__ cnt_main,
                           const float* __restrict__ cnt_ovf,
                           const float* __restrict__ ox_ovf,
                           const float* __restrict__ oy_ovf,
                           int B, int HWp, int use_ovf)
{
    int i = blockIdx.x * blockDim.x + threadIdx.x;
    if (i >= B * HWp) return;
    int b = i / HWp;
    int p = i - b * HWp;
    float* oxp = out + (size_t)b * 2 * HWp;
    float c = cnt_main[i];
    float ox = oxp[p], oy = oxp[HWp + p];
    if (use_ovf) {
        c  += cnt_ovf[i];
        ox += ox_ovf[i];
        oy += oy_ovf[i];
    }
    if (c > 0.0f) { ox /= c; oy /= c; }
    oxp[p] = ox;
    oxp[HWp + p] = oy;
    if (use_ovf) cnt_main[i] = c;
}

__global__ void fill_kernel(float* __restrict__ out,
                            const float* __restrict__ cnt,
                            int B, int H, int W)
{
    int i = blockIdx.x * blockDim.x + threadIdx.x;
    int HWp = H * W;
    if (i >= B * HWp) return;
    if (cnt[i] > 0.0f) return;  // not a hole
    int b = i / HWp;
    int p = i - b * HWp;
    int y = p / W;
    int x = p - y * W;
    const float* cb = cnt + (size_t)b * HWp;
    float* ox = out + (size_t)b * 2 * HWp;
    float* oy = ox + HWp;
    float nx = 0.0f, ny = 0.0f;
    int den = 0;
    for (int xx = x - 1; xx >= 0; --xx) {
        int q = y * W + xx;
        if (cb[q] > 0.0f) { nx += ox[q]; ny += oy[q]; ++den; break; }
    }
    for (int xx = x + 1; xx < W; ++xx) {
        int q = y * W + xx;
        if (cb[q] > 0.0f) { nx += ox[q]; ny += oy[q]; ++den; break; }
    }
    for (int yy = y - 1; yy >= 0; --yy) {
        int q = yy * W + x;
        if (cb[q] > 0.0f) { nx += ox[q]; ny += oy[q]; ++den; break; }
    }
    for (int yy = y + 1; yy < H; ++yy) {
        int q = yy * W + x;
        if (cb[q] > 0.0f) { nx += ox[q]; ny += oy[q]; ++den; break; }
    }
    if (den > 0) {
        float fd = (float)den;
        ox[p] = nx / fd;
        oy[p] = ny / fd;
    }
}

extern "C" void kernel_launch(void* const* d_in, const int* in_sizes, int n_in,
                              void* d_out, int out_size, void* d_ws, size_t ws_size,
                              hipStream_t stream) {
    const float* flow  = (const float*)d_in[0];   // (B,2,H,W)
    const float* depth = (const float*)d_in[1];   // (B,1,H,W)
    float* out = (float*)d_out;                   // (B,2,H,W)

    const int H = 1080, W = 1920;
    const int HWp = H * W;
    const int B = in_sizes[1] / HWp;
    const int total = B * HWp;

    // ws layout: [cnt_main][ovf_cnt][ovf_x][ovf_y], each B*H*W floats
    float* cnt_main = (float*)d_ws;
    size_t plane = (size_t)total;
    float* ovf = cnt_main + plane;
    int blocks = (total + 255) / 256;
    bool tiled = (ws_size >= 4 * plane * sizeof(float)) &&
                 (W % TW == 0) && (H % TH == 0);

    if (tiled) {
        // only overflow planes need zeroing; main planes fully stored by flush
        hipMemsetAsync(ovf, 0, 3 * plane * sizeof(float), stream);
        dim3 grid(W / TW, H / TH, B);   // 24 x 18 x 4
        splat_gather<<<grid, BLK, 0, stream>>>(flow, depth, cnt_main, out, ovf,
                                               B, H, W);
        merge_norm<<<blocks, 256, 0, stream>>>(out, cnt_main,
                                               ovf, ovf + plane, ovf + 2 * plane,
                                               B, HWp, 1);
    } else {
        hipMemsetAsync(out, 0, (size_t)out_size * sizeof(float), stream);
        hipMemsetAsync(cnt_main, 0, plane * sizeof(float), stream);
        splat_naive<<<blocks, 256, 0, stream>>>(flow, depth, out, cnt_main, B, H, W);
        merge_norm<<<blocks, 256, 0, stream>>>(out, cnt_main,
                                               cnt_main, cnt_main, cnt_main,
                                               B, HWp, 0);
    }
    fill_kernel<<<blocks, 256, 0, stream>>>(out, cnt_main, B, H, W);
}

// Round 6
// 295.781 us; speedup vs baseline: 13.6466x; 2.2420x over previous
//
#include <hip/hip_runtime.h>

// DepthFlowProjectionModule — B=4, H=1080, W=1920, fp32.
// Round 6: box-filter deposit. The reference adds the SAME value to all 4
// corners (iyT,ixL)+(0/1,0/1) -> that's a point mass at (iyT,ixL) convolved
// with a 2x2 box. So deposit ONCE per plane into LDS accumulator A (3 LDS
// atomics/pixel instead of 12 — attacks the measured LDS-atomic-throughput
// bound), then flush computes out[y][x] = A[y][x]+A[y][x-1]+A[y-1][x]+
// A[y-1][x-1] with plain ds_reads. Clamp-duplicate edge cases (ixL==W-1 /
// iyT==H-1: reference double-adds) handled exactly via deposit multiplier.
// Owner-gather structure as Round 5: block owns 80x60 out-tile, LDS A-planes
// 81x61 (top/left halo; halo cells duplicated across adjacent blocks — each
// copy feeds disjoint owned out-pixels), reads expanded 128x112 region.
// Far-displacement tail (~0.5%) -> overflow planes in corner form.

#define TW 80
#define TH 60
#define AW 81             // A-plane cols  (x0-1 .. x0+TW-1)
#define AH 61             // A-plane rows  (y0-1 .. y0+TH-1)
#define APIX (AW * AH)    // 4941 floats per plane; 3 planes = 59292 B
#define EW 128            // read region: gx in [x0-24, x0+103]
#define EH 112            // read region: gy in [y0-26, y0+85]; EW*EH = 14*1024
#define RX 24             // gx = x0 - RX + ex
#define RY 26             // gy = y0 - RY + ey
// displacement predicate bounds (derived so near && cell-in-A => pixel-in-read)
#define DXLO (-24)
#define DXHI 23
#define DYLO (-26)
#define DYHI 25
#define BLK 1024

__global__ __launch_bounds__(BLK, 2) void splat_box(
    const float* __restrict__ flow, const float* __restrict__ depth,
    float* __restrict__ cnt_main, float* __restrict__ out,
    float* __restrict__ ovf,      // 3 planes of B*HW: [cnt][ox][oy]
    int B, int H, int W)
{
    __shared__ float lds[3 * APIX];
    float* lc = lds;
    float* lx = lds + APIX;
    float* ly = lds + 2 * APIX;

    int tid = threadIdx.x;
    for (int q = tid; q < 3 * APIX; q += BLK) lds[q] = 0.0f;
    __syncthreads();

    int x0 = blockIdx.x * TW;
    int y0 = blockIdx.y * TH;
    int b  = blockIdx.z;
    int HWp = H * W;
    const float* fb = flow + (size_t)b * 2 * HWp;
    const float* db = depth + (size_t)b * HWp;
    float* cm  = cnt_main + (size_t)b * HWp;
    float* oxm = out + (size_t)b * 2 * HWp;
    float* oym = oxm + HWp;
    float* oc  = ovf + (size_t)b * HWp;
    float* oxo = ovf + ((size_t)B + b) * HWp;
    float* oyo = ovf + ((size_t)2 * B + b) * HWp;

    #pragma unroll
    for (int k = 0; k < (EW * EH) / BLK; ++k) {   // 14 exact iterations
        int q = tid + k * BLK;
        int ex = q & (EW - 1);
        int ey = q >> 7;
        int gx = x0 - RX + ex;
        int gy = y0 - RY + ey;
        if ((unsigned)gx >= (unsigned)W || (unsigned)gy >= (unsigned)H) continue;
        int p = gy * W + gx;
        float fx = fb[p], fy = fb[HWp + p];
        float x2 = (float)gx + fx;
        float y2 = (float)gy + fy;
        if (!(x2 >= 0.0f && y2 >= 0.0f && x2 <= (float)(W - 1) && y2 <= (float)(H - 1)))
            continue;
        float w = db[p];
        int ixL = min((int)x2, W - 1);   // x2>=0 -> trunc == floor == jnp astype+clip
        int iyT = min((int)y2, H - 1);
        int dx = ixL - gx;
        int dy = iyT - gy;
        bool near = (dx >= DXLO) & (dx <= DXHI) & (dy >= DYLO) & (dy <= DYHI);
        float vc = w, vx = -fx * w, vy = -fy * w;
        if (near) {
            // deposit once, multiplied for clamp-duplicate edge cases
            int ax = ixL - (x0 - 1);
            int ay = iyT - (y0 - 1);
            if ((unsigned)ax < (unsigned)AW && (unsigned)ay < (unsigned)AH) {
                float m = ((ixL == W - 1) ? 2.0f : 1.0f) *
                          ((iyT == H - 1) ? 2.0f : 1.0f);
                int l = ay * AW + ax;
                atomicAdd(&lc[l], vc * m);
                atomicAdd(&lx[l], vx * m);
                atomicAdd(&ly[l], vy * m);
            }
        } else if (((unsigned)(gx - x0) < (unsigned)TW) &&
                   ((unsigned)(gy - y0) < (unsigned)TH)) {
            // home block emits far tail in exact corner form
            int ixR = min(ixL + 1, W - 1);
            int iyB = min(iyT + 1, H - 1);
            #pragma unroll
            for (int c = 0; c < 4; ++c) {
                int ix = (c & 1) ? ixR : ixL;
                int iy = (c & 2) ? iyB : iyT;
                int g = iy * W + ix;
                atomicAdd(&oc[g], vc);
                atomicAdd(&oxo[g], vx);
                atomicAdd(&oyo[g], vy);
            }
        }
    }
    __syncthreads();

    // flush: 2x2 box-sum of A, plain exclusive coalesced store
    for (int q = tid; q < TW * TH; q += BLK) {
        int oyy = q / TW;
        int oxx = q - oyy * TW;
        int base = (oyy + 1) * AW + (oxx + 1);   // A[ay][ax]
        float c  = lc[base] + lc[base - 1] + lc[base - AW] + lc[base - AW - 1];
        float sx = lx[base] + lx[base - 1] + lx[base - AW] + lx[base - AW - 1];
        float sy = ly[base] + ly[base - 1] + ly[base - AW] + ly[base - AW - 1];
        int g = (y0 + oyy) * W + x0 + oxx;
        cm[g]  = c;
        oxm[g] = sx;
        oym[g] = sy;
    }
}

// fallback (ws too small / shape mismatch): direct global atomics
__global__ void splat_naive(const float* __restrict__ flow,
                            const float* __restrict__ depth,
                            float* __restrict__ out, float* __restrict__ cnt,
                            int B, int H, int W)
{
    int i = blockIdx.x * blockDim.x + threadIdx.x;
    int HWp = H * W;
    if (i >= B * HWp) return;
    int b = i / HWp;
    int p = i - b * HWp;
    int y = p / W;
    int x = p - y * W;
    const float* fb = flow + (size_t)b * 2 * HWp;
    float fx = fb[p], fy = fb[HWp + p];
    float x2 = (float)x + fx, y2 = (float)y + fy;
    if (!(x2 >= 0.0f && y2 >= 0.0f && x2 <= (float)(W - 1) && y2 <= (float)(H - 1)))
        return;
    float w = depth[i];
    int ixL = min((int)x2, W - 1);
    int iyT = min((int)y2, H - 1);
    int ixR = min(ixL + 1, W - 1);
    int iyB = min(iyT + 1, H - 1);
    float ax = -fx * w, ay = -fy * w;
    float* cb = cnt + (size_t)b * HWp;
    float* ox = out + (size_t)b * 2 * HWp;
    float* oy = ox + HWp;
    int idx[4] = {iyT * W + ixL, iyT * W + ixR, iyB * W + ixL, iyB * W + ixR};
    #pragma unroll
    for (int c = 0; c < 4; ++c) {
        atomicAdd(&cb[idx[c]], w);
        atomicAdd(&ox[idx[c]], ax);
        atomicAdd(&oy[idx[c]], ay);
    }
}

__global__ void merge_norm(float* __restrict__ out, float* __restrict__ cnt_main,
                           const float* __restrict__ cnt_ovf,
                           const float* __restrict__ ox_ovf,
                           const float* __restrict__ oy_ovf,
                           int B, int HWp, int use_ovf)
{
    int i = blockIdx.x * blockDim.x + threadIdx.x;
    if (i >= B * HWp) return;
    int b = i / HWp;
    int p = i - b * HWp;
    float* oxp = out + (size_t)b * 2 * HWp;
    float c = cnt_main[i];
    float ox = oxp[p], oy = oxp[HWp + p];
    if (use_ovf) {
        c  += cnt_ovf[i];
        ox += ox_ovf[i];
        oy += oy_ovf[i];
    }
    if (c > 0.0f) { ox /= c; oy /= c; }
    oxp[p] = ox;
    oxp[HWp + p] = oy;
    if (use_ovf) cnt_main[i] = c;
}

__global__ void fill_kernel(float* __restrict__ out,
                            const float* __restrict__ cnt,
                            int B, int H, int W)
{
    int i = blockIdx.x * blockDim.x + threadIdx.x;
    int HWp = H * W;
    if (i >= B * HWp) return;
    if (cnt[i] > 0.0f) return;  // not a hole
    int b = i / HWp;
    int p = i - b * HWp;
    int y = p / W;
    int x = p - y * W;
    const float* cb = cnt + (size_t)b * HWp;
    float* ox = out + (size_t)b * 2 * HWp;
    float* oy = ox + HWp;
    float nx = 0.0f, ny = 0.0f;
    int den = 0;
    for (int xx = x - 1; xx >= 0; --xx) {
        int q = y * W + xx;
        if (cb[q] > 0.0f) { nx += ox[q]; ny += oy[q]; ++den; break; }
    }
    for (int xx = x + 1; xx < W; ++xx) {
        int q = y * W + xx;
        if (cb[q] > 0.0f) { nx += ox[q]; ny += oy[q]; ++den; break; }
    }
    for (int yy = y - 1; yy >= 0; --yy) {
        int q = yy * W + x;
        if (cb[q] > 0.0f) { nx += ox[q]; ny += oy[q]; ++den; break; }
    }
    for (int yy = y + 1; yy < H; ++yy) {
        int q = yy * W + x;
        if (cb[q] > 0.0f) { nx += ox[q]; ny += oy[q]; ++den; break; }
    }
    if (den > 0) {
        float fd = (float)den;
        ox[p] = nx / fd;
        oy[p] = ny / fd;
    }
}

extern "C" void kernel_launch(void* const* d_in, const int* in_sizes, int n_in,
                              void* d_out, int out_size, void* d_ws, size_t ws_size,
                              hipStream_t stream) {
    const float* flow  = (const float*)d_in[0];   // (B,2,H,W)
    const float* depth = (const float*)d_in[1];   // (B,1,H,W)
    float* out = (float*)d_out;                   // (B,2,H,W)

    const int H = 1080, W = 1920;
    const int HWp = H * W;
    const int B = in_sizes[1] / HWp;
    const int total = B * HWp;

    // ws layout: [cnt_main][ovf_cnt][ovf_x][ovf_y], each B*H*W floats
    float* cnt_main = (float*)d_ws;
    size_t plane = (size_t)total;
    float* ovf = cnt_main + plane;
    int blocks = (total + 255) / 256;
    bool tiled = (ws_size >= 4 * plane * sizeof(float)) &&
                 (W % TW == 0) && (H % TH == 0);

    if (tiled) {
        // only overflow planes need zeroing; main planes fully stored by flush
        hipMemsetAsync(ovf, 0, 3 * plane * sizeof(float), stream);
        dim3 grid(W / TW, H / TH, B);   // 24 x 18 x 4
        splat_box<<<grid, BLK, 0, stream>>>(flow, depth, cnt_main, out, ovf,
                                            B, H, W);
        merge_norm<<<blocks, 256, 0, stream>>>(out, cnt_main,
                                               ovf, ovf + plane, ovf + 2 * plane,
                                               B, HWp, 1);
    } else {
        hipMemsetAsync(out, 0, (size_t)out_size * sizeof(float), stream);
        hipMemsetAsync(cnt_main, 0, plane * sizeof(float), stream);
        splat_naive<<<blocks, 256, 0, stream>>>(flow, depth, out, cnt_main, B, H, W);
        merge_norm<<<blocks, 256, 0, stream>>>(out, cnt_main,
                                               cnt_main, cnt_main, cnt_main,
                                               B, HWp, 0);
    }
    fill_kernel<<<blocks, 256, 0, stream>>>(out, cnt_main, B, H, W);
}